// Round 3
// baseline (3296.722 us; speedup 1.0000x reference)
//
#include <hip/hip_runtime.h>
#include <hip/hip_bf16.h>
#include <math.h>

typedef __hip_bfloat16 bf16;
typedef __attribute__((ext_vector_type(8))) short bf16x8;   // 8 bf16 = 4 VGPRs (guide §3)
typedef __attribute__((ext_vector_type(4))) float f32x4;

#define CDIM 768
#define HDIM 64
#define NHEAD 12
#define TSEQ 1024
#define MROWS 4096   // B*T
#define HID 3072

// ---------- transpose+convert W[K,N] fp32 -> Wt[N,K] bf16 (32x32 LDS tiles) ----------
__global__ void k_transpose(const float* __restrict__ W, bf16* __restrict__ Wt, int K, int N) {
  __shared__ float t[32][33];
  int n0 = blockIdx.x * 32, k0 = blockIdx.y * 32;
  int c = threadIdx.x, ry = threadIdx.y;
  #pragma unroll
  for (int i = 0; i < 4; i++) {
    int r = ry + 8 * i;
    t[r][c] = W[(size_t)(k0 + r) * N + n0 + c];
  }
  __syncthreads();
  #pragma unroll
  for (int i = 0; i < 4; i++) {
    int r = ry + 8 * i;
    Wt[(size_t)(n0 + r) * K + k0 + c] = __float2bfloat16(t[c][r]);
  }
}

// ---------- layernorm: h fp32 [4096,768] -> out bf16 ----------
__global__ __launch_bounds__(256) void k_ln(const float* __restrict__ h, const float* __restrict__ g,
                                            const float* __restrict__ b, bf16* __restrict__ out) {
  int row = blockIdx.x, tid = threadIdx.x;
  const float* hr = h + (size_t)row * CDIM;
  float x0 = hr[tid], x1 = hr[tid + 256], x2 = hr[tid + 512];
  float s = x0 + x1 + x2;
  float ss = x0 * x0 + x1 * x1 + x2 * x2;
  #pragma unroll
  for (int off = 32; off > 0; off >>= 1) {
    s  += __shfl_down(s, off, 64);
    ss += __shfl_down(ss, off, 64);
  }
  __shared__ float rs[4], rq[4];
  if ((tid & 63) == 0) { rs[tid >> 6] = s; rq[tid >> 6] = ss; }
  __syncthreads();
  s  = rs[0] + rs[1] + rs[2] + rs[3];
  ss = rq[0] + rq[1] + rq[2] + rq[3];
  float mu = s * (1.0f / CDIM);
  float var = ss * (1.0f / CDIM) - mu * mu;
  float rstd = rsqrtf(var + 1e-5f);
  bf16* orow = out + (size_t)row * CDIM;
  orow[tid]       = __float2bfloat16((x0 - mu) * rstd * g[tid]       + b[tid]);
  orow[tid + 256] = __float2bfloat16((x1 - mu) * rstd * g[tid + 256] + b[tid + 256]);
  orow[tid + 512] = __float2bfloat16((x2 - mu) * rstd * g[tid + 512] + b[tid + 512]);
}

// ---------- GEMM: out[M,N] = A[M,K] @ Wt[N,K]^T + bias ----------
// EPI: 0 = bias -> bf16 out; 1 = bias + gelu -> bf16 out; 2 = bias + residual -> fp32 out (in-place h)
template <int EPI>
__global__ __launch_bounds__(256) void k_gemm(const bf16* __restrict__ A, const bf16* __restrict__ Bt,
                                              const float* __restrict__ bias, const float* resid,
                                              void* out, int M, int N, int K) {
  __shared__ __align__(16) bf16 As[128 * 32];
  __shared__ __align__(16) bf16 Bs[128 * 32];
  int tid = threadIdx.x;
  int m0 = blockIdx.x * 128, n0 = blockIdx.y * 128;
  int wave = tid >> 6, lane = tid & 63;
  int wm = (wave >> 1) * 64, wn = (wave & 1) * 64;
  int lrow = lane & 15, quad = lane >> 4;
  f32x4 zz = {0.f, 0.f, 0.f, 0.f};
  f32x4 acc[4][4];
  #pragma unroll
  for (int i = 0; i < 4; i++)
    #pragma unroll
    for (int j = 0; j < 4; j++) acc[i][j] = zz;
  const bf16* Ag = A + (size_t)m0 * K;
  const bf16* Bg = Bt + (size_t)n0 * K;
  for (int k0 = 0; k0 < K; k0 += 32) {
    __syncthreads();
    #pragma unroll
    for (int i = 0; i < 2; i++) {
      int idx = i * 256 + tid;         // 0..511 ; row = idx/4, k-offset = (idx%4)*8
      int row = idx >> 2;
      int ko = (idx & 3) * 8;
      *(bf16x8*)(As + idx * 8) = *(const bf16x8*)(Ag + (size_t)row * K + k0 + ko);
      *(bf16x8*)(Bs + idx * 8) = *(const bf16x8*)(Bg + (size_t)row * K + k0 + ko);
    }
    __syncthreads();
    bf16x8 af[4], bfr[4];
    #pragma unroll
    for (int i = 0; i < 4; i++)
      af[i] = *(const bf16x8*)(As + (wm + i * 16 + lrow) * 32 + quad * 8);
    #pragma unroll
    for (int j = 0; j < 4; j++)
      bfr[j] = *(const bf16x8*)(Bs + (wn + j * 16 + lrow) * 32 + quad * 8);
    #pragma unroll
    for (int i = 0; i < 4; i++)
      #pragma unroll
      for (int j = 0; j < 4; j++)
        acc[i][j] = __builtin_amdgcn_mfma_f32_16x16x32_bf16(af[i], bfr[j], acc[i][j], 0, 0, 0);
  }
  // epilogue: D row = quad*4 + r, col = lrow (verified C/D layout, guide §3)
  #pragma unroll
  for (int i = 0; i < 4; i++) {
    int gr = m0 + wm + i * 16 + quad * 4;
    #pragma unroll
    for (int j = 0; j < 4; j++) {
      int gc = n0 + wn + j * 16 + lrow;
      float bval = bias[gc];
      #pragma unroll
      for (int r = 0; r < 4; r++) {
        int grow = gr + r;
        float vv = acc[i][j][r] + bval;
        if (EPI == 1) vv = 0.5f * vv * (1.0f + erff(vv * 0.70710678118654752f));
        if (EPI == 2) {
          ((float*)out)[(size_t)grow * N + gc] = resid[(size_t)grow * N + gc] + vv;
        } else {
          ((bf16*)out)[(size_t)grow * N + gc] = __float2bfloat16(vv);
        }
      }
    }
  }
}

// ---------- attention: vector-ALU online-softmax flash ----------
// grid (B*NHEAD, 4); block 256; thread = one q row; mask: (k%256) <= (q%256), q%256 == tid
__global__ __launch_bounds__(256) void k_attn(const bf16* __restrict__ q, const bf16* __restrict__ k,
                                              const bf16* __restrict__ v, bf16* __restrict__ y) {
  int bh = blockIdx.x;
  int b = bh / NHEAD, hh = bh % NHEAD;
  int tid = threadIdx.x;
  int qrow = blockIdx.y * 256 + tid;
  const bf16* qp = q + ((size_t)(b * TSEQ + qrow)) * CDIM + hh * HDIM;
  float Qf[64];
  #pragma unroll
  for (int c8 = 0; c8 < 8; c8++) {
    uint4 raw = *(const uint4*)(qp + c8 * 8);
    const bf16* pb = (const bf16*)&raw;
    #pragma unroll
    for (int j = 0; j < 8; j++) Qf[c8 * 8 + j] = __bfloat162float(pb[j]) * 0.125f;  // fold 1/sqrt(64)
  }
  float O[64];
  #pragma unroll
  for (int d = 0; d < 64; d++) O[d] = 0.f;
  float mx = -1e30f, lsum = 0.f;
  __shared__ float Ks[32][64];
  __shared__ float Vs[32][64];
  int wmax = tid | 63;   // wave-uniform max q%256 in this wave
  for (int kt = 0; kt < 32; kt++) {
    __syncthreads();
    {
      int kl = tid >> 3;
      int d0 = (tid & 7) * 8;
      const bf16* kp = k + ((size_t)(b * TSEQ + kt * 32 + kl)) * CDIM + hh * HDIM + d0;
      const bf16* vp = v + ((size_t)(b * TSEQ + kt * 32 + kl)) * CDIM + hh * HDIM + d0;
      uint4 kraw = *(const uint4*)kp;
      uint4 vraw = *(const uint4*)vp;
      const bf16* kbp = (const bf16*)&kraw;
      const bf16* vbp = (const bf16*)&vraw;
      #pragma unroll
      for (int j = 0; j < 8; j++) {
        Ks[kl][d0 + j] = __bfloat162float(kbp[j]);
        Vs[kl][d0 + j] = __bfloat162float(vbp[j]);
      }
    }
    __syncthreads();
    int c0 = (kt * 32) & 255;          // key%256 of first key in tile
    if (c0 > wmax) continue;           // whole tile masked for this wave (uniform)
    #pragma unroll
    for (int ch = 0; ch < 2; ch++) {
      float s[16];
      #pragma unroll
      for (int kk = 0; kk < 16; kk++) {
        int kl = ch * 16 + kk;
        const float* kr = &Ks[kl][0];
        float acc = 0.f;
        #pragma unroll
        for (int d = 0; d < 64; d += 4) {
          float4 kv = *(const float4*)(kr + d);
          acc += Qf[d] * kv.x + Qf[d + 1] * kv.y + Qf[d + 2] * kv.z + Qf[d + 3] * kv.w;
        }
        s[kk] = ((c0 + kl) <= tid) ? acc : -1e30f;
      }
      float tmax = s[0];
      #pragma unroll
      for (int kk = 1; kk < 16; kk++) tmax = fmaxf(tmax, s[kk]);
      float mnew = fmaxf(mx, tmax);
      float alpha = __expf(mx - mnew);
      lsum *= alpha;
      #pragma unroll
      for (int d = 0; d < 64; d++) O[d] *= alpha;
      #pragma unroll
      for (int kk = 0; kk < 16; kk++) {
        int kl = ch * 16 + kk;
        float p = __expf(s[kk] - mnew);
        lsum += p;
        const float* vr = &Vs[kl][0];
        #pragma unroll
        for (int d = 0; d < 64; d += 4) {
          float4 vv = *(const float4*)(vr + d);
          O[d] += p * vv.x; O[d + 1] += p * vv.y; O[d + 2] += p * vv.z; O[d + 3] += p * vv.w;
        }
      }
      mx = mnew;
    }
  }
  float inv = 1.0f / lsum;
  bf16* yp = y + ((size_t)(b * TSEQ + qrow)) * CDIM + hh * HDIM;
  #pragma unroll
  for (int d = 0; d < 64; d++) yp[d] = __float2bfloat16(O[d] * inv);
}

extern "C" void kernel_launch(void* const* d_in, const int* in_sizes, int n_in,
                              void* d_out, int out_size, void* d_ws, size_t ws_size,
                              hipStream_t stream) {
  // All inputs are fp32 per the reference's setup_inputs (jnp.float32).
  const float* x    = (const float*)d_in[0];
  const float* ln1g = (const float*)d_in[1];
  const float* ln1b = (const float*)d_in[2];
  const float* Wq   = (const float*)d_in[3];
  const float* bq   = (const float*)d_in[4];
  const float* Wk   = (const float*)d_in[5];
  const float* bk   = (const float*)d_in[6];
  const float* Wv   = (const float*)d_in[7];
  const float* bv   = (const float*)d_in[8];
  const float* Wp   = (const float*)d_in[9];
  const float* bp   = (const float*)d_in[10];
  const float* ln2g = (const float*)d_in[11];
  const float* ln2b = (const float*)d_in[12];
  const float* W1   = (const float*)d_in[13];
  const float* b1   = (const float*)d_in[14];
  const float* W2   = (const float*)d_in[15];
  const float* b2   = (const float*)d_in[16];

  char* ws = (char*)d_ws;
  size_t off = 0;
  float* h  = (float*)(ws + off); off += (size_t)MROWS * CDIM * 4;
  bf16* a   = (bf16*)(ws + off);  off += (size_t)MROWS * CDIM * 2;
  bf16* qb  = (bf16*)(ws + off);  off += (size_t)MROWS * CDIM * 2;
  bf16* kb  = (bf16*)(ws + off);  off += (size_t)MROWS * CDIM * 2;
  bf16* vb  = (bf16*)(ws + off);  off += (size_t)MROWS * CDIM * 2;
  bf16* yb  = (bf16*)(ws + off);  off += (size_t)MROWS * CDIM * 2;
  bf16* m1  = qb;  // alias: MLP hidden (4096x3072) exactly overlays q/k/v/y (all dead by then)
  bf16* wtq = (bf16*)(ws + off);  off += (size_t)CDIM * CDIM * 2;
  bf16* wtk = (bf16*)(ws + off);  off += (size_t)CDIM * CDIM * 2;
  bf16* wtv = (bf16*)(ws + off);  off += (size_t)CDIM * CDIM * 2;
  bf16* wtp = (bf16*)(ws + off);  off += (size_t)CDIM * CDIM * 2;
  bf16* wt1 = (bf16*)(ws + off);  off += (size_t)CDIM * HID * 2;
  bf16* wt2 = (bf16*)(ws + off);  off += (size_t)CDIM * HID * 2;

  int n = MROWS * CDIM;
  hipMemcpyAsync(h, x, (size_t)n * sizeof(float), hipMemcpyDeviceToDevice, stream);

  for (int l = 0; l < 4; l++) {
    const float* Wql = Wq + (size_t)l * CDIM * CDIM;
    const float* Wkl = Wk + (size_t)l * CDIM * CDIM;
    const float* Wvl = Wv + (size_t)l * CDIM * CDIM;
    const float* Wpl = Wp + (size_t)l * CDIM * CDIM;
    const float* W1l = W1 + (size_t)l * CDIM * HID;
    const float* W2l = W2 + (size_t)l * HID * CDIM;

    k_transpose<<<dim3(CDIM / 32, CDIM / 32), dim3(32, 8), 0, stream>>>(Wql, wtq, CDIM, CDIM);
    k_transpose<<<dim3(CDIM / 32, CDIM / 32), dim3(32, 8), 0, stream>>>(Wkl, wtk, CDIM, CDIM);
    k_transpose<<<dim3(CDIM / 32, CDIM / 32), dim3(32, 8), 0, stream>>>(Wvl, wtv, CDIM, CDIM);
    k_transpose<<<dim3(CDIM / 32, CDIM / 32), dim3(32, 8), 0, stream>>>(Wpl, wtp, CDIM, CDIM);
    k_transpose<<<dim3(HID / 32, CDIM / 32), dim3(32, 8), 0, stream>>>(W1l, wt1, CDIM, HID);
    k_transpose<<<dim3(CDIM / 32, HID / 32), dim3(32, 8), 0, stream>>>(W2l, wt2, HID, CDIM);

    k_ln<<<dim3(MROWS), dim3(256), 0, stream>>>(h, ln1g + l * CDIM, ln1b + l * CDIM, a);

    k_gemm<0><<<dim3(32, 6), dim3(256), 0, stream>>>(a, wtq, bq + l * CDIM, nullptr, qb, MROWS, CDIM, CDIM);
    k_gemm<0><<<dim3(32, 6), dim3(256), 0, stream>>>(a, wtk, bk + l * CDIM, nullptr, kb, MROWS, CDIM, CDIM);
    k_gemm<0><<<dim3(32, 6), dim3(256), 0, stream>>>(a, wtv, bv + l * CDIM, nullptr, vb, MROWS, CDIM, CDIM);

    k_attn<<<dim3(4 * NHEAD, 4), dim3(256), 0, stream>>>(qb, kb, vb, yb);

    k_gemm<2><<<dim3(32, 6), dim3(256), 0, stream>>>(yb, wtp, bp + l * CDIM, h, h, MROWS, CDIM, CDIM);

    k_ln<<<dim3(MROWS), dim3(256), 0, stream>>>(h, ln2g + l * CDIM, ln2b + l * CDIM, a);

    k_gemm<1><<<dim3(32, 24), dim3(256), 0, stream>>>(a, wt1, b1 + (size_t)l * HID, nullptr, m1, MROWS, HID, CDIM);
    k_gemm<2><<<dim3(32, 6), dim3(256), 0, stream>>>(m1, wt2, b2 + l * CDIM, h, h, MROWS, CDIM, HID);
  }

  hipMemcpyAsync(d_out, h, (size_t)n * sizeof(float), hipMemcpyDeviceToDevice, stream);
}

// Round 4
// 1241.152 us; speedup vs baseline: 2.6562x; 2.6562x over previous
//
#include <hip/hip_runtime.h>
#include <hip/hip_bf16.h>
#include <math.h>

typedef __hip_bfloat16 bf16;
typedef __attribute__((ext_vector_type(8))) short bf16x8;   // 8 bf16 = 4 VGPRs (guide §3)
typedef __attribute__((ext_vector_type(4))) float f32x4;

#define CDIM 768
#define HDIM 64
#define NHEAD 12
#define TSEQ 1024
#define MROWS 4096   // B*T
#define HID 3072
#define QKVN 2304    // 3*CDIM

// ---------- transpose+convert W[K,N] fp32 -> Wt[N,K] bf16 (32x32 LDS tiles) ----------
__global__ void k_transpose(const float* __restrict__ W, bf16* __restrict__ Wt, int K, int N) {
  __shared__ float t[32][33];
  int n0 = blockIdx.x * 32, k0 = blockIdx.y * 32;
  int c = threadIdx.x, ry = threadIdx.y;
  #pragma unroll
  for (int i = 0; i < 4; i++) {
    int r = ry + 8 * i;
    t[r][c] = W[(size_t)(k0 + r) * N + n0 + c];
  }
  __syncthreads();
  #pragma unroll
  for (int i = 0; i < 4; i++) {
    int r = ry + 8 * i;
    Wt[(size_t)(n0 + r) * K + k0 + c] = __float2bfloat16(t[c][r]);
  }
}

// ---------- concat q,k,v biases into [2304] ----------
__global__ void k_catbias(const float* __restrict__ bq, const float* __restrict__ bk,
                          const float* __restrict__ bv, float* __restrict__ o) {
  int i = blockIdx.x * 256 + threadIdx.x;
  if (i < QKVN) o[i] = (i < CDIM) ? bq[i] : (i < 2 * CDIM) ? bk[i - CDIM] : bv[i - 2 * CDIM];
}

// ---------- layernorm: h fp32 [4096,768] -> out bf16 ----------
__global__ __launch_bounds__(256) void k_ln(const float* __restrict__ h, const float* __restrict__ g,
                                            const float* __restrict__ b, bf16* __restrict__ out) {
  int row = blockIdx.x, tid = threadIdx.x;
  const float* hr = h + (size_t)row * CDIM;
  float x0 = hr[tid], x1 = hr[tid + 256], x2 = hr[tid + 512];
  float s = x0 + x1 + x2;
  float ss = x0 * x0 + x1 * x1 + x2 * x2;
  #pragma unroll
  for (int off = 32; off > 0; off >>= 1) {
    s  += __shfl_down(s, off, 64);
    ss += __shfl_down(ss, off, 64);
  }
  __shared__ float rs[4], rq[4];
  if ((tid & 63) == 0) { rs[tid >> 6] = s; rq[tid >> 6] = ss; }
  __syncthreads();
  s  = rs[0] + rs[1] + rs[2] + rs[3];
  ss = rq[0] + rq[1] + rq[2] + rq[3];
  float mu = s * (1.0f / CDIM);
  float var = ss * (1.0f / CDIM) - mu * mu;
  float rstd = rsqrtf(var + 1e-5f);
  bf16* orow = out + (size_t)row * CDIM;
  orow[tid]       = __float2bfloat16((x0 - mu) * rstd * g[tid]       + b[tid]);
  orow[tid + 256] = __float2bfloat16((x1 - mu) * rstd * g[tid + 256] + b[tid + 256]);
  orow[tid + 512] = __float2bfloat16((x2 - mu) * rstd * g[tid + 512] + b[tid + 512]);
}

// ---------- GEMM: out[M,N] = A[M,K] @ Wt[N,K]^T + bias ----------
// EPI: 0 = bias -> bf16 out; 1 = bias + gelu -> bf16 out; 2 = bias + residual -> fp32 out (in-place h)
template <int EPI>
__global__ __launch_bounds__(256) void k_gemm(const bf16* __restrict__ A, const bf16* __restrict__ Bt,
                                              const float* __restrict__ bias, const float* resid,
                                              void* out, int M, int N, int K) {
  __shared__ __align__(16) bf16 As[128 * 32];
  __shared__ __align__(16) bf16 Bs[128 * 32];
  int tid = threadIdx.x;
  int m0 = blockIdx.x * 128, n0 = blockIdx.y * 128;
  int wave = tid >> 6, lane = tid & 63;
  int wm = (wave >> 1) * 64, wn = (wave & 1) * 64;
  int lrow = lane & 15, quad = lane >> 4;
  f32x4 zz = {0.f, 0.f, 0.f, 0.f};
  f32x4 acc[4][4];
  #pragma unroll
  for (int i = 0; i < 4; i++)
    #pragma unroll
    for (int j = 0; j < 4; j++) acc[i][j] = zz;
  const bf16* Ag = A + (size_t)m0 * K;
  const bf16* Bg = Bt + (size_t)n0 * K;
  for (int k0 = 0; k0 < K; k0 += 32) {
    __syncthreads();
    #pragma unroll
    for (int i = 0; i < 2; i++) {
      int idx = i * 256 + tid;         // 0..511 ; row = idx/4, k-offset = (idx%4)*8
      int row = idx >> 2;
      int ko = (idx & 3) * 8;
      *(bf16x8*)(As + idx * 8) = *(const bf16x8*)(Ag + (size_t)row * K + k0 + ko);
      *(bf16x8*)(Bs + idx * 8) = *(const bf16x8*)(Bg + (size_t)row * K + k0 + ko);
    }
    __syncthreads();
    bf16x8 af[4], bfr[4];
    #pragma unroll
    for (int i = 0; i < 4; i++)
      af[i] = *(const bf16x8*)(As + (wm + i * 16 + lrow) * 32 + quad * 8);
    #pragma unroll
    for (int j = 0; j < 4; j++)
      bfr[j] = *(const bf16x8*)(Bs + (wn + j * 16 + lrow) * 32 + quad * 8);
    #pragma unroll
    for (int i = 0; i < 4; i++)
      #pragma unroll
      for (int j = 0; j < 4; j++)
        acc[i][j] = __builtin_amdgcn_mfma_f32_16x16x32_bf16(af[i], bfr[j], acc[i][j], 0, 0, 0);
  }
  // epilogue: D row = quad*4 + r, col = lrow (verified C/D layout, guide §3)
  #pragma unroll
  for (int i = 0; i < 4; i++) {
    int gr = m0 + wm + i * 16 + quad * 4;
    #pragma unroll
    for (int j = 0; j < 4; j++) {
      int gc = n0 + wn + j * 16 + lrow;
      float bval = bias[gc];
      #pragma unroll
      for (int r = 0; r < 4; r++) {
        int grow = gr + r;
        float vv = acc[i][j][r] + bval;
        if (EPI == 1) vv = 0.5f * vv * (1.0f + erff(vv * 0.70710678118654752f));
        if (EPI == 2) {
          ((float*)out)[(size_t)grow * N + gc] = resid[(size_t)grow * N + gc] + vv;
        } else {
          ((bf16*)out)[(size_t)grow * N + gc] = __float2bfloat16(vv);
        }
      }
    }
  }
}

// ---------- MFMA flash attention ----------
// qkv: [4096, 2304] bf16 (q|k|v per row). y: [4096, 768] bf16.
// grid (48, 16); block 256 = 4 waves; wave owns 16 q rows; K-tiles of 32.
// mask: (k%256) <= (q%256)
__global__ __launch_bounds__(256) void k_attn(const bf16* __restrict__ qkv, bf16* __restrict__ y) {
  int bh = blockIdx.x;
  int b = bh / NHEAD, hh = bh % NHEAD;
  int qc = blockIdx.y;                     // 64-row q chunk
  int tid = threadIdx.x;
  int wave = tid >> 6, lane = tid & 63;
  int lrow = lane & 15, quad = lane >> 4;
  int q0 = qc * 64 + wave * 16;
  int qmod = q0 & 255;
  int qcmod = (qc * 64) & 255;

  const size_t rstride = QKVN;
  const bf16* qbase = qkv + (size_t)(b * TSEQ) * rstride + hh * HDIM;
  const bf16* kbase = qbase + CDIM;
  const bf16* vbase = qbase + 2 * CDIM;

  // Q A-frags: rows q0+lrow, k = kc*32 + quad*8 + j  (stays in regs)
  bf16x8 qf[2];
  #pragma unroll
  for (int kc = 0; kc < 2; kc++)
    qf[kc] = *(const bf16x8*)(qbase + (size_t)(q0 + lrow) * rstride + kc * 32 + quad * 8);

  f32x4 zz = {0.f, 0.f, 0.f, 0.f};
  f32x4 Oacc[4];
  #pragma unroll
  for (int j = 0; j < 4; j++) Oacc[j] = zz;
  float m[4] = {-1e30f, -1e30f, -1e30f, -1e30f};
  float l[4] = {0.f, 0.f, 0.f, 0.f};

  __shared__ __align__(16) bf16 Ks[32 * 64];       // [key][d], linear-in-tid staging
  __shared__ __align__(16) bf16 Vt[64 * 40];       // [d][key], pad 40 keeps rows 16B-aligned
  __shared__ __align__(16) bf16 Pl[4][16 * 32];    // per-wave P round-trip

  for (int kt = 0; kt < 32; kt++) {
    int k0 = kt * 32;
    int kmod = k0 & 255;
    if (kmod > qcmod + 63) continue;       // block-uniform: no wave needs this tile
    __syncthreads();
    {
      // K: thread -> 8 contiguous bf16, LDS address linear in tid (conflict-free)
      int key = tid >> 3, d0 = (tid & 7) * 8;
      *(bf16x8*)(Ks + tid * 8) =
          *(const bf16x8*)(kbase + (size_t)(k0 + key) * rstride + d0);
      // V transposed: key = tid&31 spreads banks
      int vkey = tid & 31, vd0 = (tid >> 5) * 8;
      bf16x8 vv = *(const bf16x8*)(vbase + (size_t)(k0 + vkey) * rstride + vd0);
      const bf16* vp = (const bf16*)&vv;
      #pragma unroll
      for (int j = 0; j < 8; j++) Vt[(vd0 + j) * 40 + vkey] = vp[j];
    }
    __syncthreads();
    if (kmod > qmod + 15) continue;        // wave-uniform: fully masked for this wave

    // S = Q @ K^T : 2 subtiles of 16 keys, K=64 split in 2
    f32x4 s[2];
    s[0] = zz; s[1] = zz;
    #pragma unroll
    for (int sub = 0; sub < 2; sub++)
      #pragma unroll
      for (int kc = 0; kc < 2; kc++) {
        bf16x8 kf = *(const bf16x8*)(Ks + (sub * 16 + lrow) * 64 + kc * 32 + quad * 8);
        s[sub] = __builtin_amdgcn_mfma_f32_16x16x32_bf16(qf[kc], kf, s[sub], 0, 0, 0);
      }
    bool partial = (kmod + 31 > qmod);
    #pragma unroll
    for (int sub = 0; sub < 2; sub++)
      #pragma unroll
      for (int r = 0; r < 4; r++) {
        float sv = s[sub][r] * 0.125f;     // 1/sqrt(64)
        if (partial) {
          int krel = kmod + sub * 16 + lrow;
          int qrel = qmod + quad * 4 + r;
          if (krel > qrel) sv = -1e30f;
        }
        s[sub][r] = sv;
      }
    // online softmax; row r lives on the quad's 16 lanes (cols)
    float pr0[4], pr1[4], alpha[4];
    #pragma unroll
    for (int r = 0; r < 4; r++) {
      float v = fmaxf(s[0][r], s[1][r]);
      v = fmaxf(v, __shfl_xor(v, 1, 64));
      v = fmaxf(v, __shfl_xor(v, 2, 64));
      v = fmaxf(v, __shfl_xor(v, 4, 64));
      v = fmaxf(v, __shfl_xor(v, 8, 64));
      float mnew = fmaxf(m[r], v);
      alpha[r] = __expf(m[r] - mnew);
      m[r] = mnew;
      pr0[r] = __expf(s[0][r] - mnew);
      pr1[r] = __expf(s[1][r] - mnew);
      float rsum = pr0[r] + pr1[r];
      rsum += __shfl_xor(rsum, 1, 64);
      rsum += __shfl_xor(rsum, 2, 64);
      rsum += __shfl_xor(rsum, 4, 64);
      rsum += __shfl_xor(rsum, 8, 64);
      l[r] = l[r] * alpha[r] + rsum;
    }
    #pragma unroll
    for (int j = 0; j < 4; j++)
      #pragma unroll
      for (int r = 0; r < 4; r++) Oacc[j][r] *= alpha[r];
    // P: C-layout -> LDS -> A-layout (m120 pattern), bf16
    bf16* Pw = (bf16*)Pl[wave];
    #pragma unroll
    for (int r = 0; r < 4; r++) {
      Pw[(quad * 4 + r) * 32 + lrow]      = __float2bfloat16(pr0[r]);
      Pw[(quad * 4 + r) * 32 + 16 + lrow] = __float2bfloat16(pr1[r]);
    }
    bf16x8 pf = *(const bf16x8*)(Pw + lrow * 32 + quad * 8);  // same-wave dep: compiler waits lgkmcnt
    #pragma unroll
    for (int j = 0; j < 4; j++) {
      bf16x8 vf = *(const bf16x8*)(Vt + (j * 16 + lrow) * 40 + quad * 8);
      Oacc[j] = __builtin_amdgcn_mfma_f32_16x16x32_bf16(pf, vf, Oacc[j], 0, 0, 0);
    }
  }
  // epilogue: row = q0 + quad*4 + r, col = hh*64 + j*16 + lrow
  #pragma unroll
  for (int r = 0; r < 4; r++) {
    float inv = 1.0f / l[r];
    bf16* yp = y + (size_t)(b * TSEQ + q0 + quad * 4 + r) * CDIM + hh * HDIM;
    #pragma unroll
    for (int j = 0; j < 4; j++)
      yp[j * 16 + lrow] = __float2bfloat16(Oacc[j][r] * inv);
  }
}

extern "C" void kernel_launch(void* const* d_in, const int* in_sizes, int n_in,
                              void* d_out, int out_size, void* d_ws, size_t ws_size,
                              hipStream_t stream) {
  const float* x    = (const float*)d_in[0];
  const float* ln1g = (const float*)d_in[1];
  const float* ln1b = (const float*)d_in[2];
  const float* Wq   = (const float*)d_in[3];
  const float* bq   = (const float*)d_in[4];
  const float* Wk   = (const float*)d_in[5];
  const float* bk   = (const float*)d_in[6];
  const float* Wv   = (const float*)d_in[7];
  const float* bv   = (const float*)d_in[8];
  const float* Wp   = (const float*)d_in[9];
  const float* bp   = (const float*)d_in[10];
  const float* ln2g = (const float*)d_in[11];
  const float* ln2b = (const float*)d_in[12];
  const float* W1   = (const float*)d_in[13];
  const float* b1   = (const float*)d_in[14];
  const float* W2   = (const float*)d_in[15];
  const float* b2   = (const float*)d_in[16];

  char* ws = (char*)d_ws;
  size_t off = 0;
  float* h    = (float*)(ws + off); off += (size_t)MROWS * CDIM * 4;
  bf16* a     = (bf16*)(ws + off);  off += (size_t)MROWS * CDIM * 2;
  bf16* qkvb  = (bf16*)(ws + off);  off += (size_t)MROWS * QKVN * 2;
  bf16* yb    = (bf16*)(ws + off);  off += (size_t)MROWS * CDIM * 2;
  bf16* m1    = qkvb;  // alias: MLP hidden [4096,3072] overlays qkvb+yb (both dead by then)
  bf16* wqkv  = (bf16*)(ws + off);  off += (size_t)QKVN * CDIM * 2;
  bf16* wtp   = (bf16*)(ws + off);  off += (size_t)CDIM * CDIM * 2;
  bf16* wt1   = (bf16*)(ws + off);  off += (size_t)CDIM * HID * 2;
  bf16* wt2   = (bf16*)(ws + off);  off += (size_t)CDIM * HID * 2;
  float* bqkv = (float*)(ws + off); off += (size_t)QKVN * 4;

  int n = MROWS * CDIM;
  hipMemcpyAsync(h, x, (size_t)n * sizeof(float), hipMemcpyDeviceToDevice, stream);

  for (int l = 0; l < 4; l++) {
    const float* Wql = Wq + (size_t)l * CDIM * CDIM;
    const float* Wkl = Wk + (size_t)l * CDIM * CDIM;
    const float* Wvl = Wv + (size_t)l * CDIM * CDIM;
    const float* Wpl = Wp + (size_t)l * CDIM * CDIM;
    const float* W1l = W1 + (size_t)l * CDIM * HID;
    const float* W2l = W2 + (size_t)l * HID * CDIM;

    k_transpose<<<dim3(CDIM / 32, CDIM / 32), dim3(32, 8), 0, stream>>>(Wql, wqkv, CDIM, CDIM);
    k_transpose<<<dim3(CDIM / 32, CDIM / 32), dim3(32, 8), 0, stream>>>(Wkl, wqkv + (size_t)CDIM * CDIM, CDIM, CDIM);
    k_transpose<<<dim3(CDIM / 32, CDIM / 32), dim3(32, 8), 0, stream>>>(Wvl, wqkv + (size_t)2 * CDIM * CDIM, CDIM, CDIM);
    k_transpose<<<dim3(CDIM / 32, CDIM / 32), dim3(32, 8), 0, stream>>>(Wpl, wtp, CDIM, CDIM);
    k_transpose<<<dim3(HID / 32, CDIM / 32), dim3(32, 8), 0, stream>>>(W1l, wt1, CDIM, HID);
    k_transpose<<<dim3(CDIM / 32, HID / 32), dim3(32, 8), 0, stream>>>(W2l, wt2, HID, CDIM);
    k_catbias<<<dim3(9), dim3(256), 0, stream>>>(bq + l * CDIM, bk + l * CDIM, bv + l * CDIM, bqkv);

    k_ln<<<dim3(MROWS), dim3(256), 0, stream>>>(h, ln1g + l * CDIM, ln1b + l * CDIM, a);

    k_gemm<0><<<dim3(32, 18), dim3(256), 0, stream>>>(a, wqkv, bqkv, nullptr, qkvb, MROWS, QKVN, CDIM);

    k_attn<<<dim3(4 * NHEAD, 16), dim3(256), 0, stream>>>(qkvb, yb);

    k_gemm<2><<<dim3(32, 6), dim3(256), 0, stream>>>(yb, wtp, bp + l * CDIM, h, h, MROWS, CDIM, CDIM);

    k_ln<<<dim3(MROWS), dim3(256), 0, stream>>>(h, ln2g + l * CDIM, ln2b + l * CDIM, a);

    k_gemm<1><<<dim3(32, 24), dim3(256), 0, stream>>>(a, wt1, b1 + (size_t)l * HID, nullptr, m1, MROWS, HID, CDIM);
    k_gemm<2><<<dim3(32, 6), dim3(256), 0, stream>>>(m1, wt2, b2 + l * CDIM, h, h, MROWS, CDIM, HID);
  }

  hipMemcpyAsync(d_out, h, (size_t)n * sizeof(float), hipMemcpyDeviceToDevice, stream);
}

// Round 5
// 1202.210 us; speedup vs baseline: 2.7422x; 1.0324x over previous
//
#include <hip/hip_runtime.h>
#include <hip/hip_bf16.h>
#include <math.h>

typedef __hip_bfloat16 bf16;
typedef __attribute__((ext_vector_type(8))) short bf16x8;   // 8 bf16 = 4 VGPRs (guide §3)
typedef __attribute__((ext_vector_type(4))) float f32x4;

#define CDIM 768
#define HDIM 64
#define NHEAD 12
#define TSEQ 1024
#define MROWS 4096   // B*T
#define HID 3072
#define QKVN 2304    // 3*CDIM

__device__ inline void gld16(const void* g, void* l) {
  __builtin_amdgcn_global_load_lds((const __attribute__((address_space(1))) void*)g,
                                   (__attribute__((address_space(3))) void*)l, 16, 0, 0);
}

// ---------- all 6 weight transposes of one layer in ONE dispatch ----------
// fp32 [K,N] -> bf16 [N,K], 32x32 LDS tiles; block-uniform branch decode.
__global__ void k_transall(const float* __restrict__ Wq, const float* __restrict__ Wk,
                           const float* __restrict__ Wv, const float* __restrict__ Wp,
                           const float* __restrict__ W1, const float* __restrict__ W2,
                           bf16* __restrict__ wqkv, bf16* __restrict__ wtp,
                           bf16* __restrict__ wt1, bf16* __restrict__ wt2) {
  __shared__ float t[32][33];
  int blk = blockIdx.x;
  const float* src; bf16* dst; int K, N, n0, k0;
  if (blk < 1728) {            // Wq|Wk|Wv: 3 x 576 blocks of 768x768
    int w = blk / 576, id = blk % 576;
    src = (w == 0) ? Wq : (w == 1) ? Wk : Wv;
    dst = wqkv + (size_t)w * CDIM * CDIM;
    K = CDIM; N = CDIM;
    n0 = (id % 24) * 32; k0 = (id / 24) * 32;
  } else if (blk < 2304) {     // Wp: 576 blocks
    int id = blk - 1728;
    src = Wp; dst = wtp; K = CDIM; N = CDIM;
    n0 = (id % 24) * 32; k0 = (id / 24) * 32;
  } else if (blk < 4608) {     // W1: [768,3072] -> 2304 blocks
    int id = blk - 2304;
    src = W1; dst = wt1; K = CDIM; N = HID;
    n0 = (id % 96) * 32; k0 = (id / 96) * 32;
  } else {                     // W2: [3072,768] -> 2304 blocks
    int id = blk - 4608;
    src = W2; dst = wt2; K = HID; N = CDIM;
    n0 = (id % 24) * 32; k0 = (id / 24) * 32;
  }
  int c = threadIdx.x, ry = threadIdx.y;
  #pragma unroll
  for (int i = 0; i < 4; i++) {
    int r = ry + 8 * i;
    t[r][c] = src[(size_t)(k0 + r) * N + n0 + c];
  }
  __syncthreads();
  #pragma unroll
  for (int i = 0; i < 4; i++) {
    int r = ry + 8 * i;
    dst[(size_t)(n0 + r) * K + k0 + c] = __float2bfloat16(t[c][r]);
  }
}

// ---------- concat q,k,v biases into [2304] ----------
__global__ void k_catbias(const float* __restrict__ bq, const float* __restrict__ bk,
                          const float* __restrict__ bv, float* __restrict__ o) {
  int i = blockIdx.x * 256 + threadIdx.x;
  if (i < QKVN) o[i] = (i < CDIM) ? bq[i] : (i < 2 * CDIM) ? bk[i - CDIM] : bv[i - 2 * CDIM];
}

// ---------- layernorm: h fp32 [4096,768] -> out bf16 ----------
__global__ __launch_bounds__(256) void k_ln(const float* __restrict__ h, const float* __restrict__ g,
                                            const float* __restrict__ b, bf16* __restrict__ out) {
  int row = blockIdx.x, tid = threadIdx.x;
  const float* hr = h + (size_t)row * CDIM;
  float x0 = hr[tid], x1 = hr[tid + 256], x2 = hr[tid + 512];
  float s = x0 + x1 + x2;
  float ss = x0 * x0 + x1 * x1 + x2 * x2;
  #pragma unroll
  for (int off = 32; off > 0; off >>= 1) {
    s  += __shfl_down(s, off, 64);
    ss += __shfl_down(ss, off, 64);
  }
  __shared__ float rs[4], rq[4];
  if ((tid & 63) == 0) { rs[tid >> 6] = s; rq[tid >> 6] = ss; }
  __syncthreads();
  s  = rs[0] + rs[1] + rs[2] + rs[3];
  ss = rq[0] + rq[1] + rq[2] + rq[3];
  float mu = s * (1.0f / CDIM);
  float var = ss * (1.0f / CDIM) - mu * mu;
  float rstd = rsqrtf(var + 1e-5f);
  bf16* orow = out + (size_t)row * CDIM;
  orow[tid]       = __float2bfloat16((x0 - mu) * rstd * g[tid]       + b[tid]);
  orow[tid + 256] = __float2bfloat16((x1 - mu) * rstd * g[tid + 256] + b[tid + 256]);
  orow[tid + 512] = __float2bfloat16((x2 - mu) * rstd * g[tid + 512] + b[tid + 512]);
}

// ---------- GEMM: out[M,N] = A[M,K] @ Wt[N,K]^T + bias, m97 staging ----------
// EPI: 0 = bias -> bf16 out; 1 = bias + gelu -> bf16 out; 2 = bias + residual -> fp32 out (in-place h)
template <int EPI>
__global__ __launch_bounds__(256) void k_gemm(const bf16* __restrict__ A, const bf16* __restrict__ Bt,
                                              const float* __restrict__ bias, const float* resid,
                                              void* out, int M, int N, int K) {
  __shared__ __align__(16) bf16 As[128 * 32];
  __shared__ __align__(16) bf16 Bs[128 * 32];
  int tid = threadIdx.x;
  int m0 = blockIdx.x * 128, n0 = blockIdx.y * 128;
  int wave = tid >> 6, lane = tid & 63;
  int wm = (wave >> 1) * 64, wn = (wave & 1) * 64;
  int lrow = lane & 15, quad = lane >> 4;
  f32x4 zz = {0.f, 0.f, 0.f, 0.f};
  f32x4 acc[4][4];
  #pragma unroll
  for (int i = 0; i < 4; i++)
    #pragma unroll
    for (int j = 0; j < 4; j++) acc[i][j] = zz;
  const bf16* Ag = A + (size_t)m0 * K;
  const bf16* Bg = Bt + (size_t)n0 * K;
  for (int k0 = 0; k0 < K; k0 += 32) {
    __syncthreads();
    #pragma unroll
    for (int i = 0; i < 2; i++) {
      int idx = i * 256 + tid;         // 0..511 ; row = idx/4, k-offset = (idx%4)*8
      int row = idx >> 2;
      int ko = (idx & 3) * 8;
      gld16(Ag + (size_t)row * K + k0 + ko, As + idx * 8);   // lane-consecutive 16B LDS dests
      gld16(Bg + (size_t)row * K + k0 + ko, Bs + idx * 8);
    }
    __syncthreads();   // compiler drains vmcnt before s_barrier (m97 structure)
    bf16x8 af[4], bfr[4];
    #pragma unroll
    for (int i = 0; i < 4; i++)
      af[i] = *(const bf16x8*)(As + (wm + i * 16 + lrow) * 32 + quad * 8);
    #pragma unroll
    for (int j = 0; j < 4; j++)
      bfr[j] = *(const bf16x8*)(Bs + (wn + j * 16 + lrow) * 32 + quad * 8);
    #pragma unroll
    for (int i = 0; i < 4; i++)
      #pragma unroll
      for (int j = 0; j < 4; j++)
        acc[i][j] = __builtin_amdgcn_mfma_f32_16x16x32_bf16(af[i], bfr[j], acc[i][j], 0, 0, 0);
  }
  // epilogue: D row = quad*4 + r, col = lrow (verified C/D layout, guide §3)
  #pragma unroll
  for (int i = 0; i < 4; i++) {
    int gr = m0 + wm + i * 16 + quad * 4;
    #pragma unroll
    for (int j = 0; j < 4; j++) {
      int gc = n0 + wn + j * 16 + lrow;
      float bval = bias[gc];
      #pragma unroll
      for (int r = 0; r < 4; r++) {
        int grow = gr + r;
        float vv = acc[i][j][r] + bval;
        if (EPI == 1) vv = 0.5f * vv * (1.0f + erff(vv * 0.70710678118654752f));
        if (EPI == 2) {
          ((float*)out)[(size_t)grow * N + gc] = resid[(size_t)grow * N + gc] + vv;
        } else {
          ((bf16*)out)[(size_t)grow * N + gc] = __float2bfloat16(vv);
        }
      }
    }
  }
}

// ---------- MFMA flash attention ----------
// qkv: [4096, 2304] bf16 (q|k|v per row). y: [4096, 768] bf16.
// grid (48, 16); block 256 = 4 waves; wave owns 16 q rows; K-tiles of 32.
// mask: (k%256) <= (q%256)
__global__ __launch_bounds__(256) void k_attn(const bf16* __restrict__ qkv, bf16* __restrict__ y) {
  int bh = blockIdx.x;
  int b = bh / NHEAD, hh = bh % NHEAD;
  int qc = blockIdx.y;                     // 64-row q chunk
  int tid = threadIdx.x;
  int wave = tid >> 6, lane = tid & 63;
  int lrow = lane & 15, quad = lane >> 4;
  int q0 = qc * 64 + wave * 16;
  int qmod = q0 & 255;
  int qcmod = (qc * 64) & 255;

  const size_t rstride = QKVN;
  const bf16* qbase = qkv + (size_t)(b * TSEQ) * rstride + hh * HDIM;
  const bf16* kbase = qbase + CDIM;
  const bf16* vbase = qbase + 2 * CDIM;

  bf16x8 qf[2];
  #pragma unroll
  for (int kc = 0; kc < 2; kc++)
    qf[kc] = *(const bf16x8*)(qbase + (size_t)(q0 + lrow) * rstride + kc * 32 + quad * 8);

  f32x4 zz = {0.f, 0.f, 0.f, 0.f};
  f32x4 Oacc[4];
  #pragma unroll
  for (int j = 0; j < 4; j++) Oacc[j] = zz;
  float m[4] = {-1e30f, -1e30f, -1e30f, -1e30f};
  float l[4] = {0.f, 0.f, 0.f, 0.f};

  __shared__ __align__(16) bf16 Ks[32 * 64];       // [key][d]
  __shared__ __align__(16) bf16 Vt[64 * 40];       // [d][key], pad 40 keeps rows 16B-aligned
  __shared__ __align__(16) bf16 Pl[4][16 * 32];    // per-wave P round-trip

  for (int kt = 0; kt < 32; kt++) {
    int k0 = kt * 32;
    int kmod = k0 & 255;
    if (kmod > qcmod + 63) continue;       // block-uniform skip
    __syncthreads();
    {
      int key = tid >> 3, d0 = (tid & 7) * 8;
      *(bf16x8*)(Ks + tid * 8) =
          *(const bf16x8*)(kbase + (size_t)(k0 + key) * rstride + d0);
      int vkey = tid & 31, vd0 = (tid >> 5) * 8;
      bf16x8 vv = *(const bf16x8*)(vbase + (size_t)(k0 + vkey) * rstride + vd0);
      const bf16* vp = (const bf16*)&vv;
      #pragma unroll
      for (int j = 0; j < 8; j++) Vt[(vd0 + j) * 40 + vkey] = vp[j];
    }
    __syncthreads();
    if (kmod > qmod + 15) continue;        // wave-uniform skip

    f32x4 s[2];
    s[0] = zz; s[1] = zz;
    #pragma unroll
    for (int sub = 0; sub < 2; sub++)
      #pragma unroll
      for (int kc = 0; kc < 2; kc++) {
        bf16x8 kf = *(const bf16x8*)(Ks + (sub * 16 + lrow) * 64 + kc * 32 + quad * 8);
        s[sub] = __builtin_amdgcn_mfma_f32_16x16x32_bf16(qf[kc], kf, s[sub], 0, 0, 0);
      }
    bool partial = (kmod + 31 > qmod);
    #pragma unroll
    for (int sub = 0; sub < 2; sub++)
      #pragma unroll
      for (int r = 0; r < 4; r++) {
        float sv = s[sub][r] * 0.125f;     // 1/sqrt(64)
        if (partial) {
          int krel = kmod + sub * 16 + lrow;
          int qrel = qmod + quad * 4 + r;
          if (krel > qrel) sv = -1e30f;
        }
        s[sub][r] = sv;
      }
    float pr0[4], pr1[4], alpha[4];
    #pragma unroll
    for (int r = 0; r < 4; r++) {
      float v = fmaxf(s[0][r], s[1][r]);
      v = fmaxf(v, __shfl_xor(v, 1, 64));
      v = fmaxf(v, __shfl_xor(v, 2, 64));
      v = fmaxf(v, __shfl_xor(v, 4, 64));
      v = fmaxf(v, __shfl_xor(v, 8, 64));
      float mnew = fmaxf(m[r], v);
      alpha[r] = __expf(m[r] - mnew);
      m[r] = mnew;
      pr0[r] = __expf(s[0][r] - mnew);
      pr1[r] = __expf(s[1][r] - mnew);
      float rsum = pr0[r] + pr1[r];
      rsum += __shfl_xor(rsum, 1, 64);
      rsum += __shfl_xor(rsum, 2, 64);
      rsum += __shfl_xor(rsum, 4, 64);
      rsum += __shfl_xor(rsum, 8, 64);
      l[r] = l[r] * alpha[r] + rsum;
    }
    #pragma unroll
    for (int j = 0; j < 4; j++)
      #pragma unroll
      for (int r = 0; r < 4; r++) Oacc[j][r] *= alpha[r];
    bf16* Pw = (bf16*)Pl[wave];
    #pragma unroll
    for (int r = 0; r < 4; r++) {
      Pw[(quad * 4 + r) * 32 + lrow]      = __float2bfloat16(pr0[r]);
      Pw[(quad * 4 + r) * 32 + 16 + lrow] = __float2bfloat16(pr1[r]);
    }
    bf16x8 pf = *(const bf16x8*)(Pw + lrow * 32 + quad * 8);
    #pragma unroll
    for (int j = 0; j < 4; j++) {
      bf16x8 vf = *(const bf16x8*)(Vt + (j * 16 + lrow) * 40 + quad * 8);
      Oacc[j] = __builtin_amdgcn_mfma_f32_16x16x32_bf16(pf, vf, Oacc[j], 0, 0, 0);
    }
  }
  #pragma unroll
  for (int r = 0; r < 4; r++) {
    float inv = 1.0f / l[r];
    bf16* yp = y + (size_t)(b * TSEQ + q0 + quad * 4 + r) * CDIM + hh * HDIM;
    #pragma unroll
    for (int j = 0; j < 4; j++)
      yp[j * 16 + lrow] = __float2bfloat16(Oacc[j][r] * inv);
  }
}

extern "C" void kernel_launch(void* const* d_in, const int* in_sizes, int n_in,
                              void* d_out, int out_size, void* d_ws, size_t ws_size,
                              hipStream_t stream) {
  const float* x    = (const float*)d_in[0];
  const float* ln1g = (const float*)d_in[1];
  const float* ln1b = (const float*)d_in[2];
  const float* Wq   = (const float*)d_in[3];
  const float* bq   = (const float*)d_in[4];
  const float* Wk   = (const float*)d_in[5];
  const float* bk   = (const float*)d_in[6];
  const float* Wv   = (const float*)d_in[7];
  const float* bv   = (const float*)d_in[8];
  const float* Wp   = (const float*)d_in[9];
  const float* bp   = (const float*)d_in[10];
  const float* ln2g = (const float*)d_in[11];
  const float* ln2b = (const float*)d_in[12];
  const float* W1   = (const float*)d_in[13];
  const float* b1   = (const float*)d_in[14];
  const float* W2   = (const float*)d_in[15];
  const float* b2   = (const float*)d_in[16];

  char* ws = (char*)d_ws;
  size_t off = 0;
  float* h    = (float*)(ws + off); off += (size_t)MROWS * CDIM * 4;
  bf16* a     = (bf16*)(ws + off);  off += (size_t)MROWS * CDIM * 2;
  bf16* qkvb  = (bf16*)(ws + off);  off += (size_t)MROWS * QKVN * 2;
  bf16* yb    = (bf16*)(ws + off);  off += (size_t)MROWS * CDIM * 2;
  bf16* m1    = qkvb;  // alias: MLP hidden [4096,3072] overlays qkvb+yb (both dead by then)
  bf16* wqkv  = (bf16*)(ws + off);  off += (size_t)QKVN * CDIM * 2;
  bf16* wtp   = (bf16*)(ws + off);  off += (size_t)CDIM * CDIM * 2;
  bf16* wt1   = (bf16*)(ws + off);  off += (size_t)CDIM * HID * 2;
  bf16* wt2   = (bf16*)(ws + off);  off += (size_t)CDIM * HID * 2;
  float* bqkv = (float*)(ws + off); off += (size_t)QKVN * 4;

  int n = MROWS * CDIM;
  hipMemcpyAsync(h, x, (size_t)n * sizeof(float), hipMemcpyDeviceToDevice, stream);

  for (int l = 0; l < 4; l++) {
    const float* Wql = Wq + (size_t)l * CDIM * CDIM;
    const float* Wkl = Wk + (size_t)l * CDIM * CDIM;
    const float* Wvl = Wv + (size_t)l * CDIM * CDIM;
    const float* Wpl = Wp + (size_t)l * CDIM * CDIM;
    const float* W1l = W1 + (size_t)l * CDIM * HID;
    const float* W2l = W2 + (size_t)l * HID * CDIM;

    k_transall<<<dim3(6912), dim3(32, 8), 0, stream>>>(Wql, Wkl, Wvl, Wpl, W1l, W2l,
                                                       wqkv, wtp, wt1, wt2);
    k_catbias<<<dim3(9), dim3(256), 0, stream>>>(bq + l * CDIM, bk + l * CDIM, bv + l * CDIM, bqkv);

    k_ln<<<dim3(MROWS), dim3(256), 0, stream>>>(h, ln1g + l * CDIM, ln1b + l * CDIM, a);

    k_gemm<0><<<dim3(32, 18), dim3(256), 0, stream>>>(a, wqkv, bqkv, nullptr, qkvb, MROWS, QKVN, CDIM);

    k_attn<<<dim3(4 * NHEAD, 16), dim3(256), 0, stream>>>(qkvb, yb);

    k_gemm<2><<<dim3(32, 6), dim3(256), 0, stream>>>(yb, wtp, bp + l * CDIM, h, h, MROWS, CDIM, CDIM);

    k_ln<<<dim3(MROWS), dim3(256), 0, stream>>>(h, ln2g + l * CDIM, ln2b + l * CDIM, a);

    k_gemm<1><<<dim3(32, 24), dim3(256), 0, stream>>>(a, wt1, b1 + (size_t)l * HID, nullptr, m1, MROWS, HID, CDIM);
    k_gemm<2><<<dim3(32, 6), dim3(256), 0, stream>>>(m1, wt2, b2 + l * CDIM, h, h, MROWS, CDIM, HID);
  }

  hipMemcpyAsync(d_out, h, (size_t)n * sizeof(float), hipMemcpyDeviceToDevice, stream);
}

// Round 6
// 1170.865 us; speedup vs baseline: 2.8156x; 1.0268x over previous
//
#include <hip/hip_runtime.h>
#include <hip/hip_bf16.h>
#include <math.h>

typedef __hip_bfloat16 bf16;
typedef __attribute__((ext_vector_type(8))) short bf16x8;   // 8 bf16 = 4 VGPRs (guide §3)
typedef __attribute__((ext_vector_type(4))) float f32x4;

#define CDIM 768
#define HDIM 64
#define NHEAD 12
#define TSEQ 1024
#define MROWS 4096   // B*T
#define HID 3072
#define QKVN 2304    // 3*CDIM

__device__ inline void gld16(const void* g, void* l) {
  __builtin_amdgcn_global_load_lds((const __attribute__((address_space(1))) void*)g,
                                   (__attribute__((address_space(3))) void*)l, 16, 0, 0);
}

// ---------- all 6 weight transposes of one layer in ONE dispatch ----------
__global__ void k_transall(const float* __restrict__ Wq, const float* __restrict__ Wk,
                           const float* __restrict__ Wv, const float* __restrict__ Wp,
                           const float* __restrict__ W1, const float* __restrict__ W2,
                           bf16* __restrict__ wqkv, bf16* __restrict__ wtp,
                           bf16* __restrict__ wt1, bf16* __restrict__ wt2) {
  __shared__ float t[32][33];
  int blk = blockIdx.x;
  const float* src; bf16* dst; int K, N, n0, k0;
  if (blk < 1728) {            // Wq|Wk|Wv: 3 x 576 blocks of 768x768
    int w = blk / 576, id = blk % 576;
    src = (w == 0) ? Wq : (w == 1) ? Wk : Wv;
    dst = wqkv + (size_t)w * CDIM * CDIM;
    K = CDIM; N = CDIM;
    n0 = (id % 24) * 32; k0 = (id / 24) * 32;
  } else if (blk < 2304) {     // Wp
    int id = blk - 1728;
    src = Wp; dst = wtp; K = CDIM; N = CDIM;
    n0 = (id % 24) * 32; k0 = (id / 24) * 32;
  } else if (blk < 4608) {     // W1: [768,3072]
    int id = blk - 2304;
    src = W1; dst = wt1; K = CDIM; N = HID;
    n0 = (id % 96) * 32; k0 = (id / 96) * 32;
  } else {                     // W2: [3072,768]
    int id = blk - 4608;
    src = W2; dst = wt2; K = HID; N = CDIM;
    n0 = (id % 24) * 32; k0 = (id / 24) * 32;
  }
  int c = threadIdx.x, ry = threadIdx.y;
  #pragma unroll
  for (int i = 0; i < 4; i++) {
    int r = ry + 8 * i;
    t[r][c] = src[(size_t)(k0 + r) * N + n0 + c];
  }
  __syncthreads();
  #pragma unroll
  for (int i = 0; i < 4; i++) {
    int r = ry + 8 * i;
    dst[(size_t)(n0 + r) * K + k0 + c] = __float2bfloat16(t[c][r]);
  }
}

// ---------- concat q,k,v biases into [2304] ----------
__global__ void k_catbias(const float* __restrict__ bq, const float* __restrict__ bk,
                          const float* __restrict__ bv, float* __restrict__ o) {
  int i = blockIdx.x * 256 + threadIdx.x;
  if (i < QKVN) o[i] = (i < CDIM) ? bq[i] : (i < 2 * CDIM) ? bk[i - CDIM] : bv[i - 2 * CDIM];
}

// ---------- layernorm: h fp32 [4096,768] -> out bf16 ----------
__global__ __launch_bounds__(256) void k_ln(const float* __restrict__ h, const float* __restrict__ g,
                                            const float* __restrict__ b, bf16* __restrict__ out) {
  int row = blockIdx.x, tid = threadIdx.x;
  const float* hr = h + (size_t)row * CDIM;
  float x0 = hr[tid], x1 = hr[tid + 256], x2 = hr[tid + 512];
  float s = x0 + x1 + x2;
  float ss = x0 * x0 + x1 * x1 + x2 * x2;
  #pragma unroll
  for (int off = 32; off > 0; off >>= 1) {
    s  += __shfl_down(s, off, 64);
    ss += __shfl_down(ss, off, 64);
  }
  __shared__ float rs[4], rq[4];
  if ((tid & 63) == 0) { rs[tid >> 6] = s; rq[tid >> 6] = ss; }
  __syncthreads();
  s  = rs[0] + rs[1] + rs[2] + rs[3];
  ss = rq[0] + rq[1] + rq[2] + rq[3];
  float mu = s * (1.0f / CDIM);
  float var = ss * (1.0f / CDIM) - mu * mu;
  float rstd = rsqrtf(var + 1e-5f);
  bf16* orow = out + (size_t)row * CDIM;
  orow[tid]       = __float2bfloat16((x0 - mu) * rstd * g[tid]       + b[tid]);
  orow[tid + 256] = __float2bfloat16((x1 - mu) * rstd * g[tid + 256] + b[tid + 256]);
  orow[tid + 512] = __float2bfloat16((x2 - mu) * rstd * g[tid + 512] + b[tid + 512]);
}

// ---------- GEMM core loop (128x128 tile, BK=32, m97 staging) ----------
template <int EPI>
__global__ __launch_bounds__(256) void k_gemm(const bf16* __restrict__ A, const bf16* __restrict__ Bt,
                                              const float* __restrict__ bias, const float* resid,
                                              void* out, int M, int N, int K) {
  __shared__ __align__(16) bf16 As[128 * 32];
  __shared__ __align__(16) bf16 Bs[128 * 32];
  int tid = threadIdx.x;
  int m0 = blockIdx.x * 128, n0 = blockIdx.y * 128;
  int wave = tid >> 6, lane = tid & 63;
  int wm = (wave >> 1) * 64, wn = (wave & 1) * 64;
  int lrow = lane & 15, quad = lane >> 4;
  f32x4 zz = {0.f, 0.f, 0.f, 0.f};
  f32x4 acc[4][4];
  #pragma unroll
  for (int i = 0; i < 4; i++)
    #pragma unroll
    for (int j = 0; j < 4; j++) acc[i][j] = zz;
  const bf16* Ag = A + (size_t)m0 * K;
  const bf16* Bg = Bt + (size_t)n0 * K;
  for (int k0 = 0; k0 < K; k0 += 32) {
    __syncthreads();
    #pragma unroll
    for (int i = 0; i < 2; i++) {
      int idx = i * 256 + tid;
      int row = idx >> 2;
      int ko = (idx & 3) * 8;
      gld16(Ag + (size_t)row * K + k0 + ko, As + idx * 8);
      gld16(Bg + (size_t)row * K + k0 + ko, Bs + idx * 8);
    }
    __syncthreads();
    bf16x8 af[4], bfr[4];
    #pragma unroll
    for (int i = 0; i < 4; i++)
      af[i] = *(const bf16x8*)(As + (wm + i * 16 + lrow) * 32 + quad * 8);
    #pragma unroll
    for (int j = 0; j < 4; j++)
      bfr[j] = *(const bf16x8*)(Bs + (wn + j * 16 + lrow) * 32 + quad * 8);
    #pragma unroll
    for (int i = 0; i < 4; i++)
      #pragma unroll
      for (int j = 0; j < 4; j++)
        acc[i][j] = __builtin_amdgcn_mfma_f32_16x16x32_bf16(af[i], bfr[j], acc[i][j], 0, 0, 0);
  }
  #pragma unroll
  for (int i = 0; i < 4; i++) {
    int gr = m0 + wm + i * 16 + quad * 4;
    #pragma unroll
    for (int j = 0; j < 4; j++) {
      int gc = n0 + wn + j * 16 + lrow;
      float bval = bias[gc];
      #pragma unroll
      for (int r = 0; r < 4; r++) {
        int grow = gr + r;
        float vv = acc[i][j][r] + bval;
        if (EPI == 1) vv = 0.5f * vv * (1.0f + erff(vv * 0.70710678118654752f));
        ((bf16*)out)[(size_t)grow * N + gc] = __float2bfloat16(vv);
      }
    }
  }
}

// ---------- split-K GEMM: h[M,N] += A[M,K]@Bt^T + bias (fp32 h in place) ----------
// grid (M/128, N/128, SPLITS); each z-slice handles K/SPLITS; bias added by z==0.
// Epilogue: native fp32 atomic add (unsafeAtomicAdd -> global_atomic_add_f32).
__global__ __launch_bounds__(256) void k_gemm_sk(const bf16* __restrict__ A, const bf16* __restrict__ Bt,
                                                 const float* __restrict__ bias,
                                                 float* __restrict__ h, int M, int N, int K) {
  __shared__ __align__(16) bf16 As[128 * 32];
  __shared__ __align__(16) bf16 Bs[128 * 32];
  int tid = threadIdx.x;
  int m0 = blockIdx.x * 128, n0 = blockIdx.y * 128;
  int splits = gridDim.z;
  int kchunk = K / splits;
  int kb = blockIdx.z * kchunk;
  int wave = tid >> 6, lane = tid & 63;
  int wm = (wave >> 1) * 64, wn = (wave & 1) * 64;
  int lrow = lane & 15, quad = lane >> 4;
  f32x4 zz = {0.f, 0.f, 0.f, 0.f};
  f32x4 acc[4][4];
  #pragma unroll
  for (int i = 0; i < 4; i++)
    #pragma unroll
    for (int j = 0; j < 4; j++) acc[i][j] = zz;
  const bf16* Ag = A + (size_t)m0 * K;
  const bf16* Bg = Bt + (size_t)n0 * K;
  for (int k0 = kb; k0 < kb + kchunk; k0 += 32) {
    __syncthreads();
    #pragma unroll
    for (int i = 0; i < 2; i++) {
      int idx = i * 256 + tid;
      int row = idx >> 2;
      int ko = (idx & 3) * 8;
      gld16(Ag + (size_t)row * K + k0 + ko, As + idx * 8);
      gld16(Bg + (size_t)row * K + k0 + ko, Bs + idx * 8);
    }
    __syncthreads();
    bf16x8 af[4], bfr[4];
    #pragma unroll
    for (int i = 0; i < 4; i++)
      af[i] = *(const bf16x8*)(As + (wm + i * 16 + lrow) * 32 + quad * 8);
    #pragma unroll
    for (int j = 0; j < 4; j++)
      bfr[j] = *(const bf16x8*)(Bs + (wn + j * 16 + lrow) * 32 + quad * 8);
    #pragma unroll
    for (int i = 0; i < 4; i++)
      #pragma unroll
      for (int j = 0; j < 4; j++)
        acc[i][j] = __builtin_amdgcn_mfma_f32_16x16x32_bf16(af[i], bfr[j], acc[i][j], 0, 0, 0);
  }
  bool addb = (blockIdx.z == 0);
  #pragma unroll
  for (int i = 0; i < 4; i++) {
    int gr = m0 + wm + i * 16 + quad * 4;
    #pragma unroll
    for (int j = 0; j < 4; j++) {
      int gc = n0 + wn + j * 16 + lrow;
      float bval = addb ? bias[gc] : 0.f;
      #pragma unroll
      for (int r = 0; r < 4; r++) {
        int grow = gr + r;
        unsafeAtomicAdd(&h[(size_t)grow * N + gc], acc[i][j][r] + bval);
      }
    }
  }
}

// ---------- MFMA flash attention ----------
__global__ __launch_bounds__(256) void k_attn(const bf16* __restrict__ qkv, bf16* __restrict__ y) {
  int bh = blockIdx.x;
  int b = bh / NHEAD, hh = bh % NHEAD;
  int qc = blockIdx.y;
  int tid = threadIdx.x;
  int wave = tid >> 6, lane = tid & 63;
  int lrow = lane & 15, quad = lane >> 4;
  int q0 = qc * 64 + wave * 16;
  int qmod = q0 & 255;
  int qcmod = (qc * 64) & 255;

  const size_t rstride = QKVN;
  const bf16* qbase = qkv + (size_t)(b * TSEQ) * rstride + hh * HDIM;
  const bf16* kbase = qbase + CDIM;
  const bf16* vbase = qbase + 2 * CDIM;

  bf16x8 qf[2];
  #pragma unroll
  for (int kc = 0; kc < 2; kc++)
    qf[kc] = *(const bf16x8*)(qbase + (size_t)(q0 + lrow) * rstride + kc * 32 + quad * 8);

  f32x4 zz = {0.f, 0.f, 0.f, 0.f};
  f32x4 Oacc[4];
  #pragma unroll
  for (int j = 0; j < 4; j++) Oacc[j] = zz;
  float m[4] = {-1e30f, -1e30f, -1e30f, -1e30f};
  float l[4] = {0.f, 0.f, 0.f, 0.f};

  __shared__ __align__(16) bf16 Ks[32 * 64];
  __shared__ __align__(16) bf16 Vt[64 * 40];
  __shared__ __align__(16) bf16 Pl[4][16 * 32];

  for (int kt = 0; kt < 32; kt++) {
    int k0 = kt * 32;
    int kmod = k0 & 255;
    if (kmod > qcmod + 63) continue;
    __syncthreads();
    {
      int key = tid >> 3, d0 = (tid & 7) * 8;
      *(bf16x8*)(Ks + tid * 8) =
          *(const bf16x8*)(kbase + (size_t)(k0 + key) * rstride + d0);
      int vkey = tid & 31, vd0 = (tid >> 5) * 8;
      bf16x8 vv = *(const bf16x8*)(vbase + (size_t)(k0 + vkey) * rstride + vd0);
      const bf16* vp = (const bf16*)&vv;
      #pragma unroll
      for (int j = 0; j < 8; j++) Vt[(vd0 + j) * 40 + vkey] = vp[j];
    }
    __syncthreads();
    if (kmod > qmod + 15) continue;

    f32x4 s[2];
    s[0] = zz; s[1] = zz;
    #pragma unroll
    for (int sub = 0; sub < 2; sub++)
      #pragma unroll
      for (int kc = 0; kc < 2; kc++) {
        bf16x8 kf = *(const bf16x8*)(Ks + (sub * 16 + lrow) * 64 + kc * 32 + quad * 8);
        s[sub] = __builtin_amdgcn_mfma_f32_16x16x32_bf16(qf[kc], kf, s[sub], 0, 0, 0);
      }
    bool partial = (kmod + 31 > qmod);
    #pragma unroll
    for (int sub = 0; sub < 2; sub++)
      #pragma unroll
      for (int r = 0; r < 4; r++) {
        float sv = s[sub][r] * 0.125f;
        if (partial) {
          int krel = kmod + sub * 16 + lrow;
          int qrel = qmod + quad * 4 + r;
          if (krel > qrel) sv = -1e30f;
        }
        s[sub][r] = sv;
      }
    float pr0[4], pr1[4], alpha[4];
    #pragma unroll
    for (int r = 0; r < 4; r++) {
      float v = fmaxf(s[0][r], s[1][r]);
      v = fmaxf(v, __shfl_xor(v, 1, 64));
      v = fmaxf(v, __shfl_xor(v, 2, 64));
      v = fmaxf(v, __shfl_xor(v, 4, 64));
      v = fmaxf(v, __shfl_xor(v, 8, 64));
      float mnew = fmaxf(m[r], v);
      alpha[r] = __expf(m[r] - mnew);
      m[r] = mnew;
      pr0[r] = __expf(s[0][r] - mnew);
      pr1[r] = __expf(s[1][r] - mnew);
      float rsum = pr0[r] + pr1[r];
      rsum += __shfl_xor(rsum, 1, 64);
      rsum += __shfl_xor(rsum, 2, 64);
      rsum += __shfl_xor(rsum, 4, 64);
      rsum += __shfl_xor(rsum, 8, 64);
      l[r] = l[r] * alpha[r] + rsum;
    }
    #pragma unroll
    for (int j = 0; j < 4; j++)
      #pragma unroll
      for (int r = 0; r < 4; r++) Oacc[j][r] *= alpha[r];
    bf16* Pw = (bf16*)Pl[wave];
    #pragma unroll
    for (int r = 0; r < 4; r++) {
      Pw[(quad * 4 + r) * 32 + lrow]      = __float2bfloat16(pr0[r]);
      Pw[(quad * 4 + r) * 32 + 16 + lrow] = __float2bfloat16(pr1[r]);
    }
    bf16x8 pf = *(const bf16x8*)(Pw + lrow * 32 + quad * 8);
    #pragma unroll
    for (int j = 0; j < 4; j++) {
      bf16x8 vf = *(const bf16x8*)(Vt + (j * 16 + lrow) * 40 + quad * 8);
      Oacc[j] = __builtin_amdgcn_mfma_f32_16x16x32_bf16(pf, vf, Oacc[j], 0, 0, 0);
    }
  }
  #pragma unroll
  for (int r = 0; r < 4; r++) {
    float inv = 1.0f / l[r];
    bf16* yp = y + (size_t)(b * TSEQ + q0 + quad * 4 + r) * CDIM + hh * HDIM;
    #pragma unroll
    for (int j = 0; j < 4; j++)
      yp[j * 16 + lrow] = __float2bfloat16(Oacc[j][r] * inv);
  }
}

extern "C" void kernel_launch(void* const* d_in, const int* in_sizes, int n_in,
                              void* d_out, int out_size, void* d_ws, size_t ws_size,
                              hipStream_t stream) {
  const float* x    = (const float*)d_in[0];
  const float* ln1g = (const float*)d_in[1];
  const float* ln1b = (const float*)d_in[2];
  const float* Wq   = (const float*)d_in[3];
  const float* bq   = (const float*)d_in[4];
  const float* Wk   = (const float*)d_in[5];
  const float* bk   = (const float*)d_in[6];
  const float* Wv   = (const float*)d_in[7];
  const float* bv   = (const float*)d_in[8];
  const float* Wp   = (const float*)d_in[9];
  const float* bp   = (const float*)d_in[10];
  const float* ln2g = (const float*)d_in[11];
  const float* ln2b = (const float*)d_in[12];
  const float* W1   = (const float*)d_in[13];
  const float* b1   = (const float*)d_in[14];
  const float* W2   = (const float*)d_in[15];
  const float* b2   = (const float*)d_in[16];

  char* ws = (char*)d_ws;
  size_t off = 0;
  float* h    = (float*)(ws + off); off += (size_t)MROWS * CDIM * 4;
  bf16* a     = (bf16*)(ws + off);  off += (size_t)MROWS * CDIM * 2;
  bf16* qkvb  = (bf16*)(ws + off);  off += (size_t)MROWS * QKVN * 2;
  bf16* yb    = (bf16*)(ws + off);  off += (size_t)MROWS * CDIM * 2;
  bf16* m1    = qkvb;  // alias: MLP hidden [4096,3072] overlays qkvb+yb (both dead by then)
  bf16* wqkv  = (bf16*)(ws + off);  off += (size_t)QKVN * CDIM * 2;
  bf16* wtp   = (bf16*)(ws + off);  off += (size_t)CDIM * CDIM * 2;
  bf16* wt1   = (bf16*)(ws + off);  off += (size_t)CDIM * HID * 2;
  bf16* wt2   = (bf16*)(ws + off);  off += (size_t)CDIM * HID * 2;
  float* bqkv = (float*)(ws + off); off += (size_t)QKVN * 4;

  int n = MROWS * CDIM;
  hipMemcpyAsync(h, x, (size_t)n * sizeof(float), hipMemcpyDeviceToDevice, stream);

  for (int l = 0; l < 4; l++) {
    const float* Wql = Wq + (size_t)l * CDIM * CDIM;
    const float* Wkl = Wk + (size_t)l * CDIM * CDIM;
    const float* Wvl = Wv + (size_t)l * CDIM * CDIM;
    const float* Wpl = Wp + (size_t)l * CDIM * CDIM;
    const float* W1l = W1 + (size_t)l * CDIM * HID;
    const float* W2l = W2 + (size_t)l * HID * CDIM;

    k_transall<<<dim3(6912), dim3(32, 8), 0, stream>>>(Wql, Wkl, Wvl, Wpl, W1l, W2l,
                                                       wqkv, wtp, wt1, wt2);
    k_catbias<<<dim3(9), dim3(256), 0, stream>>>(bq + l * CDIM, bk + l * CDIM, bv + l * CDIM, bqkv);

    k_ln<<<dim3(MROWS), dim3(256), 0, stream>>>(h, ln1g + l * CDIM, ln1b + l * CDIM, a);

    k_gemm<0><<<dim3(32, 18), dim3(256), 0, stream>>>(a, wqkv, bqkv, nullptr, qkvb, MROWS, QKVN, CDIM);

    k_attn<<<dim3(4 * NHEAD, 16), dim3(256), 0, stream>>>(qkvb, yb);

    // attn-proj: h += yb @ wtp^T + bp   (split-K x4: 768 blocks, 3/CU)
    k_gemm_sk<<<dim3(32, 6, 4), dim3(256), 0, stream>>>(yb, wtp, bp + l * CDIM, h, MROWS, CDIM, CDIM);

    k_ln<<<dim3(MROWS), dim3(256), 0, stream>>>(h, ln2g + l * CDIM, ln2b + l * CDIM, a);

    k_gemm<1><<<dim3(32, 24), dim3(256), 0, stream>>>(a, wt1, b1 + (size_t)l * HID, nullptr, m1, MROWS, HID, CDIM);

    // MLP2: h += m1 @ wt2^T + b2   (split-K x4: 768 blocks, 3/CU, 24 iters each)
    k_gemm_sk<<<dim3(32, 6, 4), dim3(256), 0, stream>>>(m1, wt2, b2 + l * CDIM, h, MROWS, CDIM, HID);
  }

  hipMemcpyAsync(d_out, h, (size_t)n * sizeof(float), hipMemcpyDeviceToDevice, stream);
}